// Round 4
// baseline (173.935 us; speedup 1.0000x reference)
//
#include <hip/hip_runtime.h>
#include <math.h>

#define TOKENS 16384
#define DIM 4096
#define NE 64
#define BM 32
#define NKT 64
#define KTW 16

// ws float offsets
#define WS_DENOM 0
#define WS_PROXY 64
#define WS_COUNT 128
#define WS_META  256            // float4 per token: 65536 floats
#define WS_WST   65792          // 786432 ushorts: W re-layout, 3 planes x 2 halves

typedef __attribute__((ext_vector_type(8))) short bf16x8;
typedef __attribute__((ext_vector_type(16))) float f32x16;

__device__ __forceinline__ ushort f2bf(float f) {
    uint u = __float_as_uint(f);
    return (ushort)((u + 0x7FFFu + ((u >> 16) & 1u)) >> 16);
}
__device__ __forceinline__ float bf2f(ushort h) {
    return __uint_as_float(((uint)h) << 16);
}
__device__ __forceinline__ void split3(float f, ushort& h, ushort& m, ushort& l) {
    h = f2bf(f);
    float r = f - bf2f(h);
    m = f2bf(r);
    r -= bf2f(m);
    l = f2bf(r);
}
__device__ __forceinline__ uint pack2(ushort a, ushort b) {
    return (uint)a | ((uint)b << 16);
}

__global__ void init_kernel(float* ws) {
    int i = threadIdx.x;
    if (i < 192) ws[i] = 0.0f;
}

// W [4096][64] f32 -> wst ushort layout:
//   widx(p,h,kt,s,lane,j) = (p*2+h)*131072 + kt*2048 + s*512 + lane*8 + j
//   value = plane-p bf16 of W[kt*64 + s*16 + (lane>>5)*8 + j][h*32 + (lane&31)]
// so a wave's B-fragment load for (p,h,kt,s) is lane*16B contiguous.
__global__ __launch_bounds__(256) void wconv(const float* __restrict__ W,
                                             ushort* __restrict__ wst) {
    __shared__ float t[64][68];
    const int kt = blockIdx.x;
    const int tid = threadIdx.x;
    #pragma unroll
    for (int i = 0; i < 4; i++) {
        int idx = tid + i * 256;
        int r = idx >> 4, c4 = idx & 15;
        float4 v = *(const float4*)(W + (size_t)(kt * 64 + r) * NE + c4 * 4);
        *(float4*)(&t[r][c4 * 4]) = v;
    }
    __syncthreads();
    #pragma unroll
    for (int i = 0; i < 2; i++) {
        int slot = tid + i * 256;          // 0..511
        int h = slot >> 8;
        int s = (slot >> 6) & 3;
        int lane = slot & 63;
        int e = h * 32 + (lane & 31);
        int klb = s * 16 + (lane >> 5) * 8;
        uint H[4], M[4], L[4];
        #pragma unroll
        for (int j = 0; j < 4; j++) {
            ushort h0, m0, l0, h1, m1, l1;
            split3(t[klb + 2 * j][e], h0, m0, l0);
            split3(t[klb + 2 * j + 1][e], h1, m1, l1);
            H[j] = pack2(h0, h1);
            M[j] = pack2(m0, m1);
            L[j] = pack2(l0, l1);
        }
        size_t o = (size_t)h * 131072 + (size_t)kt * 2048 + s * 512 + lane * 8;
        *(uint4*)(wst + o)          = make_uint4(H[0], H[1], H[2], H[3]);
        *(uint4*)(wst + 262144 + o) = make_uint4(M[0], M[1], M[2], M[3]);
        *(uint4*)(wst + 524288 + o) = make_uint4(L[0], L[1], L[2], L[3]);
    }
}

__global__ __launch_bounds__(256, 2) void gate_main(const float* __restrict__ x,
        const ushort* __restrict__ wst, const float* __restrict__ bias,
        float* __restrict__ ws) {

    // per-wave private x tiles: 3 planes x [32 rows][64 k] bf16, swizzled
    __shared__ __align__(16) char xsm[4][12288];
    __shared__ float lg[BM][66];
    __shared__ float tmax[BM], tinv[BM];
    __shared__ float pp[4][NE];

    const int tid = threadIdx.x;
    const int wave = tid >> 6, lane = tid & 63;
    const int l31 = lane & 31, hi = lane >> 5;
    const int tBase = blockIdx.x * BM;

    const int lrow = lane >> 4, lc = lane & 15;
    const float* xbase = x + (size_t)(tBase + lrow) * DIM + lc * 4;

    char* XB = xsm[wave];

    f32x16 acc0, acc1;
    #pragma unroll
    for (int i = 0; i < 16; i++) { acc0[i] = 0.0f; acc1[i] = 0.0f; }

    float4 cur[8], nxt[8];

    auto loadx = [&](float4* dst, int kt) {
        const float* p0 = xbase + kt * 64;
        #pragma unroll
        for (int j = 0; j < 8; j++)
            dst[j] = *(const float4*)(p0 + (size_t)j * 4 * DIM);
    };

    auto splitwrite = [&](const float4* v) {
        #pragma unroll
        for (int j = 0; j < 8; j++) {
            int row = j * 4 + lrow;
            uint base = (uint)row * 128
                      + (uint)(((lc >> 1) ^ (row & 7)) * 16) + (uint)((lc & 1) * 8);
            float f[4] = {v[j].x, v[j].y, v[j].z, v[j].w};
            ushort h[4], m[4], l[4];
            #pragma unroll
            for (int q = 0; q < 4; q++) split3(f[q], h[q], m[q], l[q]);
            uint2 H = {pack2(h[0], h[1]), pack2(h[2], h[3])};
            uint2 M = {pack2(m[0], m[1]), pack2(m[2], m[3])};
            uint2 L = {pack2(l[0], l[1]), pack2(l[2], l[3])};
            *(uint2*)(XB + base)        = H;
            *(uint2*)(XB + 4096 + base) = M;
            *(uint2*)(XB + 8192 + base) = L;
        }
    };

    loadx(cur, wave);

    #pragma unroll 2
    for (int i = 0; i < KTW; i++) {
        int kt = wave + i * 4;
        if (i + 1 < KTW) loadx(nxt, kt + 4);
        splitwrite(cur);
        const ushort* wkt = wst + (size_t)kt * 2048 + lane * 8;
        #pragma unroll
        for (int s = 0; s < 4; s++) {
            uint ro = (uint)l31 * 128 + (uint)((((s * 2 + hi) ^ (l31 & 7))) * 16);
            bf16x8 ah = *(const bf16x8*)(XB + ro);
            bf16x8 am = *(const bf16x8*)(XB + 4096 + ro);
            bf16x8 al = *(const bf16x8*)(XB + 8192 + ro);
            const ushort* wp = wkt + s * 512;
            bf16x8 wh0 = *(const bf16x8*)(wp);
            bf16x8 wh1 = *(const bf16x8*)(wp + 131072);
            bf16x8 wm0 = *(const bf16x8*)(wp + 262144);
            bf16x8 wm1 = *(const bf16x8*)(wp + 393216);
            bf16x8 wl0 = *(const bf16x8*)(wp + 524288);
            bf16x8 wl1 = *(const bf16x8*)(wp + 655360);
            acc0 = __builtin_amdgcn_mfma_f32_32x32x16_bf16(ah, wh0, acc0, 0, 0, 0);
            acc1 = __builtin_amdgcn_mfma_f32_32x32x16_bf16(ah, wh1, acc1, 0, 0, 0);
            acc0 = __builtin_amdgcn_mfma_f32_32x32x16_bf16(ah, wm0, acc0, 0, 0, 0);
            acc1 = __builtin_amdgcn_mfma_f32_32x32x16_bf16(ah, wm1, acc1, 0, 0, 0);
            acc0 = __builtin_amdgcn_mfma_f32_32x32x16_bf16(am, wh0, acc0, 0, 0, 0);
            acc1 = __builtin_amdgcn_mfma_f32_32x32x16_bf16(am, wh1, acc1, 0, 0, 0);
            acc0 = __builtin_amdgcn_mfma_f32_32x32x16_bf16(am, wm0, acc0, 0, 0, 0);
            acc1 = __builtin_amdgcn_mfma_f32_32x32x16_bf16(am, wm1, acc1, 0, 0, 0);
            acc0 = __builtin_amdgcn_mfma_f32_32x32x16_bf16(ah, wl0, acc0, 0, 0, 0);
            acc1 = __builtin_amdgcn_mfma_f32_32x32x16_bf16(ah, wl1, acc1, 0, 0, 0);
            acc0 = __builtin_amdgcn_mfma_f32_32x32x16_bf16(al, wh0, acc0, 0, 0, 0);
            acc1 = __builtin_amdgcn_mfma_f32_32x32x16_bf16(al, wh1, acc1, 0, 0, 0);
        }
        #pragma unroll
        for (int j = 0; j < 8; j++) cur[j] = nxt[j];
    }

    // cross-wave K reduction (C/D: col=lane&31, row=(reg&3)+8*(reg>>2)+4*hi)
    {
        float b0 = bias[l31], b1 = bias[32 + l31];
        for (int p = 0; p < 4; p++) {
            if (wave == p) {
                #pragma unroll
                for (int reg = 0; reg < 16; reg++) {
                    int grow = (reg & 3) + 8 * (reg >> 2) + 4 * hi;
                    if (p == 0) {
                        lg[grow][l31]      = acc0[reg] + b0;
                        lg[grow][32 + l31] = acc1[reg] + b1;
                    } else {
                        lg[grow][l31]      += acc0[reg];
                        lg[grow][32 + l31] += acc1[reg];
                    }
                }
            }
            __syncthreads();
        }
    }

    // per-token softmax + top-2 (threads 0..31)
    if (tid < BM) {
        const int t = tid;
        float m = -INFINITY;
        #pragma unroll
        for (int e = 0; e < NE; e++) m = fmaxf(m, lg[t][e]);
        float s = 0.0f;
        float v0 = -INFINITY, v1 = -INFINITY;
        int i0 = 0, i1 = 1;
        #pragma unroll
        for (int e = 0; e < NE; e++) {
            float l = lg[t][e];
            s += expf(l - m);
            if (l > v0) { v1 = v0; i1 = i0; v0 = l; i0 = e; }
            else if (l > v1) { v1 = l; i1 = e; }
        }
        float inv = 1.0f / s;
        tmax[t] = m; tinv[t] = inv;
        float g0 = expf(v0 - m) * inv;
        float g1 = expf(v1 - m) * inv;
        float4 mt4;
        mt4.x = __int_as_float(i0);
        mt4.y = __int_as_float(i1);
        mt4.z = g0; mt4.w = g1;
        ((float4*)(ws + WS_META))[tBase + t] = mt4;
        atomicAdd(&ws[WS_DENOM + i0], g0);
        atomicAdd(&ws[WS_DENOM + i1], g1);
        atomicAdd(&ws[WS_COUNT + i0], 1.0f);
        atomicAdd(&ws[WS_COUNT + i1], 1.0f);
    }
    __syncthreads();

    // per-expert gate-score partial sums (density_proxy numerator)
    {
        int e = tid & 63;
        int grp = tid >> 6;    // 0..3, 8 tokens each
        float p = 0.0f;
        #pragma unroll
        for (int r = 0; r < 8; r++) {
            int t = grp * 8 + r;
            p += expf(lg[t][e] - tmax[t]) * tinv[t];
        }
        pp[grp][e] = p;
    }
    __syncthreads();
    if (tid < NE) {
        float s = pp[0][tid] + pp[1][tid] + pp[2][tid] + pp[3][tid];
        atomicAdd(&ws[WS_PROXY + tid], s);
    }
}

__global__ __launch_bounds__(256) void gate_write(const float* __restrict__ ws,
                                                  float* __restrict__ out) {
    const float CAP = 16384.0f;
    int tid = threadIdx.x;
    int tl = tid >> 4;
    int e4 = (tid & 15) * 4;
    int t = blockIdx.x * 16 + tl;
    float4 mt = ((const float4*)(ws + WS_META))[t];
    int i0 = __float_as_int(mt.x), i1 = __float_as_int(mt.y);
    float s0 = mt.z * CAP / (ws[i0] + 1e-6f);
    float s1 = mt.w * CAP / (ws[i1] + 1e-6f);
    float4 v = {0.0f, 0.0f, 0.0f, 0.0f};
    float* vp = (float*)&v;
    #pragma unroll
    for (int j = 0; j < 4; j++) {
        int e = e4 + j;
        vp[j] = (e == i0) ? s0 : ((e == i1) ? s1 : 0.0f);
    }
    *(float4*)(out + (size_t)t * NE + e4) = v;
}

__global__ void gate_loss(const float* __restrict__ ws, float* __restrict__ out) {
    int e = threadIdx.x;
    float v = ws[WS_PROXY + e] * ws[WS_COUNT + e];
    #pragma unroll
    for (int off = 32; off; off >>= 1) v += __shfl_down(v, off);
    if (e == 0) {
        out[(size_t)TOKENS * NE] = 64.0f * v / (16384.0f * 16384.0f);
    }
}

extern "C" void kernel_launch(void* const* d_in, const int* in_sizes, int n_in,
                              void* d_out, int out_size, void* d_ws, size_t ws_size,
                              hipStream_t stream) {
    const float* x = (const float*)d_in[0];
    const float* W = (const float*)d_in[1];
    const float* b = (const float*)d_in[2];
    float* out = (float*)d_out;
    float* ws = (float*)d_ws;
    ushort* wst = (ushort*)(ws + WS_WST);

    hipLaunchKernelGGL(init_kernel, dim3(1), dim3(256), 0, stream, ws);
    hipLaunchKernelGGL(wconv, dim3(64), dim3(256), 0, stream, W, wst);
    hipLaunchKernelGGL(gate_main, dim3(TOKENS / BM), dim3(256), 0, stream,
                       x, wst, b, ws);
    hipLaunchKernelGGL(gate_write, dim3(TOKENS / 16), dim3(256), 0, stream, ws, out);
    hipLaunchKernelGGL(gate_loss, dim3(1), dim3(64), 0, stream, ws, out);
}

// Round 5
// 164.357 us; speedup vs baseline: 1.0583x; 1.0583x over previous
//
#include <hip/hip_runtime.h>
#include <math.h>

#define TOKENS 16384
#define DIM 4096
#define NE 64
#define BM 32
#define NKT 64
#define KTW 16

// ws float offsets
#define WS_DENOM 0
#define WS_PROXY 64
#define WS_COUNT 128
#define WS_META  256            // float4 per token: 65536 floats
#define WS_WST   65792          // 786432 ushorts: W re-layout, 3 planes x 2 halves

typedef __attribute__((ext_vector_type(8))) short bf16x8;
typedef __attribute__((ext_vector_type(16))) float f32x16;

__device__ __forceinline__ ushort f2bf(float f) {
    uint u = __float_as_uint(f);
    return (ushort)((u + 0x7FFFu + ((u >> 16) & 1u)) >> 16);
}
__device__ __forceinline__ float bf2f(ushort h) {
    return __uint_as_float(((uint)h) << 16);
}
__device__ __forceinline__ void split3(float f, ushort& h, ushort& m, ushort& l) {
    h = f2bf(f);
    float r = f - bf2f(h);
    m = f2bf(r);
    r -= bf2f(m);
    l = f2bf(r);
}
__device__ __forceinline__ uint pack2(ushort a, ushort b) {
    return (uint)a | ((uint)b << 16);
}

// truncation split of a float pair -> packed bf16 pair per plane
__device__ __forceinline__ void splitpair(float f0, float f1,
                                          uint& H, uint& M, uint& L) {
    uint u0 = __float_as_uint(f0), u1 = __float_as_uint(f1);
    H = (u0 >> 16) | (u1 & 0xFFFF0000u);
    float r0 = f0 - __uint_as_float(u0 & 0xFFFF0000u);
    float r1 = f1 - __uint_as_float(u1 & 0xFFFF0000u);
    uint v0 = __float_as_uint(r0), v1 = __float_as_uint(r1);
    M = (v0 >> 16) | (v1 & 0xFFFF0000u);
    float q0 = r0 - __uint_as_float(v0 & 0xFFFF0000u);
    float q1 = r1 - __uint_as_float(v1 & 0xFFFF0000u);
    uint w0 = __float_as_uint(q0), w1 = __float_as_uint(q1);
    L = (w0 >> 16) | (w1 & 0xFFFF0000u);
}

__global__ void init_kernel(float* ws) {
    int i = threadIdx.x;
    if (i < 192) ws[i] = 0.0f;
}

// W [4096][64] f32 -> wst ushort layout:
//   addr(p,h,kt,s,lane,j) = p*262144 + h*131072 + kt*2048 + s*512 + lane*8 + j
//   value = plane-p bf16 of W[kt*64 + s*16 + (lane>>5)*8 + j][h*32 + (lane&31)]
__global__ __launch_bounds__(256) void wconv(const float* __restrict__ W,
                                             ushort* __restrict__ wst) {
    __shared__ float t[64][68];
    const int kt = blockIdx.x;
    const int tid = threadIdx.x;
    #pragma unroll
    for (int i = 0; i < 4; i++) {
        int idx = tid + i * 256;
        int r = idx >> 4, c4 = idx & 15;
        float4 v = *(const float4*)(W + (size_t)(kt * 64 + r) * NE + c4 * 4);
        *(float4*)(&t[r][c4 * 4]) = v;
    }
    __syncthreads();
    #pragma unroll
    for (int i = 0; i < 2; i++) {
        int slot = tid + i * 256;          // 0..511
        int h = slot >> 8;
        int s = (slot >> 6) & 3;
        int lane = slot & 63;
        int e = h * 32 + (lane & 31);
        int klb = s * 16 + (lane >> 5) * 8;
        uint H[4], M[4], L[4];
        #pragma unroll
        for (int j = 0; j < 4; j++) {
            ushort h0, m0, l0, h1, m1, l1;
            split3(t[klb + 2 * j][e], h0, m0, l0);
            split3(t[klb + 2 * j + 1][e], h1, m1, l1);
            H[j] = pack2(h0, h1);
            M[j] = pack2(m0, m1);
            L[j] = pack2(l0, l1);
        }
        size_t o = (size_t)h * 131072 + (size_t)kt * 2048 + s * 512 + lane * 8;
        *(uint4*)(wst + o)          = make_uint4(H[0], H[1], H[2], H[3]);
        *(uint4*)(wst + 262144 + o) = make_uint4(M[0], M[1], M[2], M[3]);
        *(uint4*)(wst + 524288 + o) = make_uint4(L[0], L[1], L[2], L[3]);
    }
}

__global__ __launch_bounds__(256, 2) void gate_main(const float* __restrict__ x,
        const ushort* __restrict__ wst, const float* __restrict__ bias,
        float* __restrict__ ws) {

    __shared__ float lg[BM][66];
    __shared__ float tmax[BM], tinv[BM];
    __shared__ float pp[4][NE];

    const int tid = threadIdx.x;
    const int wave = tid >> 6, lane = tid & 63;
    const int l31 = lane & 31, hi = lane >> 5;
    const int tBase = blockIdx.x * BM;

    // per-lane A-fragment base: row = tBase + (lane&31), k chunk = hi*8
    const float* xb = x + (size_t)(tBase + l31) * DIM + hi * 8;

    f32x16 acc0, acc1;
    #pragma unroll
    for (int i = 0; i < 16; i++) { acc0[i] = 0.0f; acc1[i] = 0.0f; }

    float4 cur[8], nxt[8];

    auto xload = [&](float4* d, int kt) {
        const float* p = xb + kt * 64;
        #pragma unroll
        for (int s = 0; s < 4; s++) {
            d[2 * s]     = *(const float4*)(p + s * 16);
            d[2 * s + 1] = *(const float4*)(p + s * 16 + 4);
        }
    };

    xload(cur, wave);

    for (int i = 0; i < KTW; i++) {
        const int kt = wave + 4 * i;
        // ---- W fragment loads FIRST (issue-order: W before x prefetch)
        const ushort* wb = wst + (size_t)kt * 2048 + (size_t)lane * 8;
        bf16x8 wf[3][2][4];
        #pragma unroll
        for (int p = 0; p < 3; p++)
            #pragma unroll
            for (int h = 0; h < 2; h++)
                #pragma unroll
                for (int s = 0; s < 4; s++)
                    wf[p][h][s] = *(const bf16x8*)(wb
                        + (size_t)(p * 2 + h) * 131072 + s * 512);
        // ---- x prefetch for next kt (after W issues)
        if (i + 1 < KTW) xload(nxt, kt + 4);
        // ---- split + MFMA per 16-k step
        #pragma unroll
        for (int s = 0; s < 4; s++) {
            float4 a = cur[2 * s], b = cur[2 * s + 1];
            uint4 H, M, L;
            splitpair(a.x, a.y, H.x, M.x, L.x);
            splitpair(a.z, a.w, H.y, M.y, L.y);
            splitpair(b.x, b.y, H.z, M.z, L.z);
            splitpair(b.z, b.w, H.w, M.w, L.w);
            bf16x8 ah = *(bf16x8*)&H;
            bf16x8 am = *(bf16x8*)&M;
            bf16x8 al = *(bf16x8*)&L;
            acc0 = __builtin_amdgcn_mfma_f32_32x32x16_bf16(ah, wf[0][0][s], acc0, 0, 0, 0);
            acc1 = __builtin_amdgcn_mfma_f32_32x32x16_bf16(ah, wf[0][1][s], acc1, 0, 0, 0);
            acc0 = __builtin_amdgcn_mfma_f32_32x32x16_bf16(ah, wf[1][0][s], acc0, 0, 0, 0);
            acc1 = __builtin_amdgcn_mfma_f32_32x32x16_bf16(ah, wf[1][1][s], acc1, 0, 0, 0);
            acc0 = __builtin_amdgcn_mfma_f32_32x32x16_bf16(am, wf[0][0][s], acc0, 0, 0, 0);
            acc1 = __builtin_amdgcn_mfma_f32_32x32x16_bf16(am, wf[0][1][s], acc1, 0, 0, 0);
            acc0 = __builtin_amdgcn_mfma_f32_32x32x16_bf16(am, wf[1][0][s], acc0, 0, 0, 0);
            acc1 = __builtin_amdgcn_mfma_f32_32x32x16_bf16(am, wf[1][1][s], acc1, 0, 0, 0);
            acc0 = __builtin_amdgcn_mfma_f32_32x32x16_bf16(ah, wf[2][0][s], acc0, 0, 0, 0);
            acc1 = __builtin_amdgcn_mfma_f32_32x32x16_bf16(ah, wf[2][1][s], acc1, 0, 0, 0);
            acc0 = __builtin_amdgcn_mfma_f32_32x32x16_bf16(al, wf[0][0][s], acc0, 0, 0, 0);
            acc1 = __builtin_amdgcn_mfma_f32_32x32x16_bf16(al, wf[0][1][s], acc1, 0, 0, 0);
        }
        if (i + 1 < KTW) {
            #pragma unroll
            for (int j = 0; j < 8; j++) cur[j] = nxt[j];
        }
    }

    // cross-wave K reduction (C/D: col=lane&31, row=(reg&3)+8*(reg>>2)+4*hi)
    {
        float b0 = bias[l31], b1 = bias[32 + l31];
        for (int p = 0; p < 4; p++) {
            if (wave == p) {
                #pragma unroll
                for (int reg = 0; reg < 16; reg++) {
                    int grow = (reg & 3) + 8 * (reg >> 2) + 4 * hi;
                    if (p == 0) {
                        lg[grow][l31]      = acc0[reg] + b0;
                        lg[grow][32 + l31] = acc1[reg] + b1;
                    } else {
                        lg[grow][l31]      += acc0[reg];
                        lg[grow][32 + l31] += acc1[reg];
                    }
                }
            }
            __syncthreads();
        }
    }

    // per-token softmax + top-2 (threads 0..31)
    if (tid < BM) {
        const int t = tid;
        float m = -INFINITY;
        #pragma unroll
        for (int e = 0; e < NE; e++) m = fmaxf(m, lg[t][e]);
        float s = 0.0f;
        float v0 = -INFINITY, v1 = -INFINITY;
        int i0 = 0, i1 = 1;
        #pragma unroll
        for (int e = 0; e < NE; e++) {
            float l = lg[t][e];
            s += expf(l - m);
            if (l > v0) { v1 = v0; i1 = i0; v0 = l; i0 = e; }
            else if (l > v1) { v1 = l; i1 = e; }
        }
        float inv = 1.0f / s;
        tmax[t] = m; tinv[t] = inv;
        float g0 = expf(v0 - m) * inv;
        float g1 = expf(v1 - m) * inv;
        float4 mt4;
        mt4.x = __int_as_float(i0);
        mt4.y = __int_as_float(i1);
        mt4.z = g0; mt4.w = g1;
        ((float4*)(ws + WS_META))[tBase + t] = mt4;
        atomicAdd(&ws[WS_DENOM + i0], g0);
        atomicAdd(&ws[WS_DENOM + i1], g1);
        atomicAdd(&ws[WS_COUNT + i0], 1.0f);
        atomicAdd(&ws[WS_COUNT + i1], 1.0f);
    }
    __syncthreads();

    // per-expert gate-score partial sums (density_proxy numerator)
    {
        int e = tid & 63;
        int grp = tid >> 6;    // 0..3, 8 tokens each
        float p = 0.0f;
        #pragma unroll
        for (int r = 0; r < 8; r++) {
            int t = grp * 8 + r;
            p += expf(lg[t][e] - tmax[t]) * tinv[t];
        }
        pp[grp][e] = p;
    }
    __syncthreads();
    if (tid < NE) {
        float s = pp[0][tid] + pp[1][tid] + pp[2][tid] + pp[3][tid];
        atomicAdd(&ws[WS_PROXY + tid], s);
    }
}

__global__ __launch_bounds__(256) void gate_write(const float* __restrict__ ws,
                                                  float* __restrict__ out) {
    const float CAP = 16384.0f;
    int tid = threadIdx.x;
    int tl = tid >> 4;
    int e4 = (tid & 15) * 4;
    int t = blockIdx.x * 16 + tl;
    float4 mt = ((const float4*)(ws + WS_META))[t];
    int i0 = __float_as_int(mt.x), i1 = __float_as_int(mt.y);
    float s0 = mt.z * CAP / (ws[i0] + 1e-6f);
    float s1 = mt.w * CAP / (ws[i1] + 1e-6f);
    float4 v = {0.0f, 0.0f, 0.0f, 0.0f};
    float* vp = (float*)&v;
    #pragma unroll
    for (int j = 0; j < 4; j++) {
        int e = e4 + j;
        vp[j] = (e == i0) ? s0 : ((e == i1) ? s1 : 0.0f);
    }
    *(float4*)(out + (size_t)t * NE + e4) = v;
}

__global__ void gate_loss(const float* __restrict__ ws, float* __restrict__ out) {
    int e = threadIdx.x;
    float v = ws[WS_PROXY + e] * ws[WS_COUNT + e];
    #pragma unroll
    for (int off = 32; off; off >>= 1) v += __shfl_down(v, off);
    if (e == 0) {
        out[(size_t)TOKENS * NE] = 64.0f * v / (16384.0f * 16384.0f);
    }
}

extern "C" void kernel_launch(void* const* d_in, const int* in_sizes, int n_in,
                              void* d_out, int out_size, void* d_ws, size_t ws_size,
                              hipStream_t stream) {
    const float* x = (const float*)d_in[0];
    const float* W = (const float*)d_in[1];
    const float* b = (const float*)d_in[2];
    float* out = (float*)d_out;
    float* ws = (float*)d_ws;
    ushort* wst = (ushort*)(ws + WS_WST);

    hipLaunchKernelGGL(init_kernel, dim3(1), dim3(256), 0, stream, ws);
    hipLaunchKernelGGL(wconv, dim3(64), dim3(256), 0, stream, W, wst);
    hipLaunchKernelGGL(gate_main, dim3(TOKENS / BM), dim3(256), 0, stream,
                       x, wst, b, ws);
    hipLaunchKernelGGL(gate_write, dim3(TOKENS / 16), dim3(256), 0, stream, ws, out);
    hipLaunchKernelGGL(gate_loss, dim3(1), dim3(64), 0, stream, ws, out);
}

// Round 6
// 161.192 us; speedup vs baseline: 1.0791x; 1.0196x over previous
//
#include <hip/hip_runtime.h>
#include <math.h>

#define TOKENS 16384
#define DIM 4096
#define NE 64

// ws float offsets
#define WS_DENOM 0
#define WS_PROXY 64
#define WS_COUNT 128
#define WS_META  256            // float4 per token: 65536 floats
#define WS_WST   65792          // 524288 ushorts = 1 MB, W f16 2-plane relayout

typedef __attribute__((ext_vector_type(8))) _Float16 f16x8;
typedef __attribute__((ext_vector_type(4))) float f32x4;

__global__ void init_kernel(float* ws) {
    int i = threadIdx.x;
    if (i < 192) ws[i] = 0.0f;
}

// W [4096][64] f32 -> f16 2-plane frag layout (W pre-scaled by 4096):
//   halves at ((p*4+ecol)*64 + kt)*1024 + step*512 + lane*8 + j
//   value = plane-p f16 of 4096*W[kt*64 + step*32 + (lane>>4)*8 + j][ecol*16 + (lane&15)]
// so a wave's B-fragment load for (p,ecol,kt,step) is lane*16B contiguous.
__global__ __launch_bounds__(256) void wconv(const float* __restrict__ W,
                                             ushort* __restrict__ wst) {
    __shared__ float t[64][68];
    const int kt = blockIdx.x, tid = threadIdx.x;
    #pragma unroll
    for (int i = 0; i < 4; i++) {
        int idx = tid + i * 256;
        int r = idx >> 4, c4 = idx & 15;
        float4 v = *(const float4*)(W + (size_t)(kt * 64 + r) * NE + c4 * 4);
        *(float4*)(&t[r][c4 * 4]) = v;
    }
    __syncthreads();
    #pragma unroll
    for (int it = 0; it < 2; it++) {
        int slot = tid + it * 256;            // 0..511
        int ecol = slot >> 7;
        int step = (slot >> 6) & 1;
        int lane = slot & 63;
        int e  = ecol * 16 + (lane & 15);
        int kb = step * 32 + (lane >> 4) * 8;
        f16x8 H, M;
        #pragma unroll
        for (int j = 0; j < 8; j++) {
            float f = 4096.0f * t[kb + j][e];
            _Float16 h = (_Float16)f;
            H[j] = h;
            M[j] = (_Float16)(f - (float)h);
        }
        size_t o0 = ((size_t)(ecol * 64 + kt)) * 1024 + step * 512 + lane * 8;
        size_t o1 = ((size_t)((4 + ecol) * 64 + kt)) * 1024 + step * 512 + lane * 8;
        *(f16x8*)(wst + o0) = H;
        *(f16x8*)(wst + o1) = M;
    }
}

__device__ __forceinline__ void split8(const float4& a, const float4& b,
                                       f16x8& h, f16x8& m) {
    float f[8] = {a.x, a.y, a.z, a.w, b.x, b.y, b.z, b.w};
    #pragma unroll
    for (int j = 0; j < 8; j++) {
        float v = 512.0f * f[j];
        _Float16 hh = (_Float16)v;
        h[j] = hh;
        m[j] = (_Float16)(v - (float)hh);
    }
}

__global__ __launch_bounds__(256, 4) void gate_main(const float* __restrict__ x,
        const ushort* __restrict__ wst, const float* __restrict__ bias,
        float* __restrict__ ws) {

    __shared__ float sl[4][16][64];
    __shared__ float lg[16][68];
    __shared__ float tmax[16], tinv[16];
    __shared__ float pp[4][NE];

    const int tid = threadIdx.x, wave = tid >> 6, lane = tid & 63;
    const int tg = blockIdx.x;
    const int l15 = lane & 15, kc = lane >> 4;
    const float* xr = x + (size_t)(tg * 16 + l15) * DIM + kc * 8;
    const ushort* wb = wst + lane * 8;

    f32x4 acc[4];
    #pragma unroll
    for (int ec = 0; ec < 4; ec++)
        #pragma unroll
        for (int p = 0; p < 4; p++) acc[ec][p] = 0.0f;

    f16x8 wh0[4], wm0[4], wh1[4], wm1[4];
    float4 c0, c1, c2, c3;

    const int ktb = wave * 16;
    // prologue: issue W step0(ktb), then x(ktb)
    {
        const size_t kto = (size_t)ktb * 1024;
        #pragma unroll
        for (int ec = 0; ec < 4; ec++) {
            wh0[ec] = *(const f16x8*)(wb + (size_t)(ec * 64) * 1024 + kto);
            wm0[ec] = *(const f16x8*)(wb + (size_t)((4 + ec) * 64) * 1024 + kto);
        }
        const float* xp = xr + ktb * 64;
        c0 = *(const float4*)(xp);
        c1 = *(const float4*)(xp + 4);
        c2 = *(const float4*)(xp + 32);
        c3 = *(const float4*)(xp + 36);
    }

    #pragma unroll
    for (int i = 0; i < 16; i++) {
        const int kt = ktb + i;
        const size_t kto = (size_t)kt * 1024;
        // split current x tile (waits x; W-next still flying was issued after x)
        f16x8 ah0, am0, ah1, am1;
        split8(c0, c1, ah0, am0);
        split8(c2, c3, ah1, am1);
        // issue W step1(kt)
        #pragma unroll
        for (int ec = 0; ec < 4; ec++) {
            wh1[ec] = *(const f16x8*)(wb + (size_t)(ec * 64) * 1024 + kto + 512);
            wm1[ec] = *(const f16x8*)(wb + (size_t)((4 + ec) * 64) * 1024 + kto + 512);
        }
        // issue x(kt+1)
        if (i < 15) {
            const float* xn = xr + (kt + 1) * 64;
            c0 = *(const float4*)(xn);
            c1 = *(const float4*)(xn + 4);
            c2 = *(const float4*)(xn + 32);
            c3 = *(const float4*)(xn + 36);
        }
        // MFMA step0 (waits wh0/wm0 only; x + W-step1 keep flying per in-order vmcnt)
        #pragma unroll
        for (int ec = 0; ec < 4; ec++) {
            acc[ec] = __builtin_amdgcn_mfma_f32_16x16x32_f16(ah0, wh0[ec], acc[ec], 0, 0, 0);
            acc[ec] = __builtin_amdgcn_mfma_f32_16x16x32_f16(am0, wh0[ec], acc[ec], 0, 0, 0);
            acc[ec] = __builtin_amdgcn_mfma_f32_16x16x32_f16(ah0, wm0[ec], acc[ec], 0, 0, 0);
        }
        // issue W step0(kt+1)
        if (i < 15) {
            const size_t kto2 = kto + 1024;
            #pragma unroll
            for (int ec = 0; ec < 4; ec++) {
                wh0[ec] = *(const f16x8*)(wb + (size_t)(ec * 64) * 1024 + kto2);
                wm0[ec] = *(const f16x8*)(wb + (size_t)((4 + ec) * 64) * 1024 + kto2);
            }
        }
        // MFMA step1
        #pragma unroll
        for (int ec = 0; ec < 4; ec++) {
            acc[ec] = __builtin_amdgcn_mfma_f32_16x16x32_f16(ah1, wh1[ec], acc[ec], 0, 0, 0);
            acc[ec] = __builtin_amdgcn_mfma_f32_16x16x32_f16(am1, wh1[ec], acc[ec], 0, 0, 0);
            acc[ec] = __builtin_amdgcn_mfma_f32_16x16x32_f16(ah1, wm1[ec], acc[ec], 0, 0, 0);
        }
    }

    // stash per-wave partials (C/D: col(expert)=lane&15, row(token)=(lane>>4)*4+reg)
    #pragma unroll
    for (int ec = 0; ec < 4; ec++)
        #pragma unroll
        for (int p = 0; p < 4; p++)
            sl[wave][kc * 4 + p][ec * 16 + l15] = acc[ec][p];
    __syncthreads();

    // fixed-order cross-wave sum + rescale + bias -> logits
    {
        int t = tid >> 4, e4 = (tid & 15) * 4;
        #pragma unroll
        for (int j = 0; j < 4; j++) {
            int e = e4 + j;
            lg[t][e] = (sl[0][t][e] + sl[1][t][e] + sl[2][t][e] + sl[3][t][e])
                       * (1.0f / 2097152.0f) + bias[e];
        }
    }
    __syncthreads();

    // per-token softmax + top-2 (threads 0..15)
    if (tid < 16) {
        const int t = tid;
        float m = -INFINITY;
        #pragma unroll
        for (int e = 0; e < NE; e++) m = fmaxf(m, lg[t][e]);
        float s = 0.0f;
        float v0 = -INFINITY, v1 = -INFINITY;
        int i0 = 0, i1 = 1;
        #pragma unroll
        for (int e = 0; e < NE; e++) {
            float l = lg[t][e];
            s += expf(l - m);
            if (l > v0) { v1 = v0; i1 = i0; v0 = l; i0 = e; }
            else if (l > v1) { v1 = l; i1 = e; }
        }
        float inv = 1.0f / s;
        tmax[t] = m; tinv[t] = inv;
        float g0 = expf(v0 - m) * inv;
        float g1 = expf(v1 - m) * inv;
        float4 mt4;
        mt4.x = __int_as_float(i0);
        mt4.y = __int_as_float(i1);
        mt4.z = g0; mt4.w = g1;
        ((float4*)(ws + WS_META))[tg * 16 + t] = mt4;
        atomicAdd(&ws[WS_DENOM + i0], g0);
        atomicAdd(&ws[WS_DENOM + i1], g1);
        atomicAdd(&ws[WS_COUNT + i0], 1.0f);
        atomicAdd(&ws[WS_COUNT + i1], 1.0f);
    }
    __syncthreads();

    // per-expert gate-score partial sums (density_proxy numerator)
    {
        int e = tid & 63;
        int grp = tid >> 6;    // 0..3, 4 tokens each
        float p = 0.0f;
        #pragma unroll
        for (int r = 0; r < 4; r++) {
            int t = grp * 4 + r;
            p += expf(lg[t][e] - tmax[t]) * tinv[t];
        }
        pp[grp][e] = p;
    }
    __syncthreads();
    if (tid < NE) {
        float s = pp[0][tid] + pp[1][tid] + pp[2][tid] + pp[3][tid];
        atomicAdd(&ws[WS_PROXY + tid], s);
    }
}

__global__ __launch_bounds__(256) void gate_write(const float* __restrict__ ws,
                                                  float* __restrict__ out) {
    const float CAP = 16384.0f;
    int tid = threadIdx.x;
    int tl = tid >> 4;
    int e4 = (tid & 15) * 4;
    int t = blockIdx.x * 16 + tl;
    float4 mt = ((const float4*)(ws + WS_META))[t];
    int i0 = __float_as_int(mt.x), i1 = __float_as_int(mt.y);
    float s0 = mt.z * CAP / (ws[i0] + 1e-6f);
    float s1 = mt.w * CAP / (ws[i1] + 1e-6f);
    float4 v = {0.0f, 0.0f, 0.0f, 0.0f};
    float* vp = (float*)&v;
    #pragma unroll
    for (int j = 0; j < 4; j++) {
        int e = e4 + j;
        vp[j] = (e == i0) ? s0 : ((e == i1) ? s1 : 0.0f);
    }
    *(float4*)(out + (size_t)t * NE + e4) = v;
}

__global__ void gate_loss(const float* __restrict__ ws, float* __restrict__ out) {
    int e = threadIdx.x;
    float v = ws[WS_PROXY + e] * ws[WS_COUNT + e];
    #pragma unroll
    for (int off = 32; off; off >>= 1) v += __shfl_down(v, off);
    if (e == 0) {
        out[(size_t)TOKENS * NE] = 64.0f * v / (16384.0f * 16384.0f);
    }
}

extern "C" void kernel_launch(void* const* d_in, const int* in_sizes, int n_in,
                              void* d_out, int out_size, void* d_ws, size_t ws_size,
                              hipStream_t stream) {
    const float* x = (const float*)d_in[0];
    const float* W = (const float*)d_in[1];
    const float* b = (const float*)d_in[2];
    float* out = (float*)d_out;
    float* ws = (float*)d_ws;
    ushort* wst = (ushort*)(ws + WS_WST);

    hipLaunchKernelGGL(init_kernel, dim3(1), dim3(256), 0, stream, ws);
    hipLaunchKernelGGL(wconv, dim3(64), dim3(256), 0, stream, W, wst);
    hipLaunchKernelGGL(gate_main, dim3(TOKENS / 16), dim3(256), 0, stream,
                       x, wst, b, ws);
    hipLaunchKernelGGL(gate_write, dim3(TOKENS / 16), dim3(256), 0, stream, ws, out);
    hipLaunchKernelGGL(gate_loss, dim3(1), dim3(64), 0, stream, ws, out);
}